// Round 1
// baseline (697.678 us; speedup 1.0000x reference)
//
#include <hip/hip_runtime.h>

#define D 256

typedef __attribute__((ext_vector_type(8))) short s16x8;
typedef __attribute__((ext_vector_type(4))) float f32x4;

static __device__ __forceinline__ unsigned short f2b(float f) {
    unsigned u = __float_as_uint(f);
    unsigned r = (u + 0x7fffu + ((u >> 16) & 1u)) >> 16;   // RNE
    return (unsigned short)r;
}
static __device__ __forceinline__ unsigned pack2(float a, float b) {
    return (unsigned)f2b(a) | ((unsigned)f2b(b) << 16);
}

// ---- cast both weight matrices to bf16, stored in MFMA B-fragment order ----
// Fragment layout (16x16x32 bf16): for tile t of 16 rows, k-tile kt (32 k),
// lane l = (row&15) | (((k>>3)&3)<<4) holds 8 contiguous bf16.
// unit index (16B units) = (t<<9) + (kt<<6) + lane.
__global__ void prep_w_kernel(const float* __restrict__ lw, const float* __restrict__ sw,
                              unsigned short* __restrict__ wTf) {
    int i = blockIdx.x * 256 + threadIdx.x;
    float v = (i < D * D) ? lw[i] : sw[i - D * D];
    int n = i >> 8;          // 0..511: concatenated [loc; std] output col
    int k = i & 255;
    int lane = (n & 15) | (((k >> 3) & 3) << 4);
    int unit = ((n >> 4) << 9) + ((k >> 5) << 6) + lane;
    wTf[unit * 8 + (k & 7)] = f2b(v);
}

// ---- cast vrepr to bf16, 32B read / 16B write per thread ----
__global__ void conv_v_kernel(const float* __restrict__ vr, unsigned short* __restrict__ vb, int n8) {
    int i = blockIdx.x * 256 + threadIdx.x;
    if (i < n8) {
        float4 f0 = ((const float4*)vr)[2 * i];
        float4 f1 = ((const float4*)vr)[2 * i + 1];
        uint4 o;
        o.x = pack2(f0.x, f0.y);
        o.y = pack2(f0.z, f0.w);
        o.z = pack2(f1.x, f1.y);
        o.w = pack2(f1.z, f1.w);
        ((uint4*)vb)[i] = o;
    }
}

// ---- histogram of target indices; records each edge's arrival rank ----
__global__ void hist_kernel(const int* __restrict__ tidx, int* __restrict__ cnt,
                            int* __restrict__ rank, int E) {
    int e = blockIdx.x * blockDim.x + threadIdx.x;
    if (e < E) rank[e] = atomicAdd(&cnt[tidx[e]], 1);
}

// ---- single-block exclusive scan over V counts ----
__global__ void scan_kernel(const int* __restrict__ cnt, int* __restrict__ off, int V, int E) {
    __shared__ int sums[1024];
    int tid = threadIdx.x;
    int CH = (V + 1023) >> 10;
    int beg = tid * CH;
    int end = min(beg + CH, V);
    int s = 0;
    for (int i = beg; i < end; ++i) s += cnt[i];
    sums[tid] = s;
    __syncthreads();
    for (int ofs = 1; ofs < 1024; ofs <<= 1) {
        int v = (tid >= ofs) ? sums[tid - ofs] : 0;
        __syncthreads();
        sums[tid] += v;
        __syncthreads();
    }
    int run = (tid == 0) ? 0 : sums[tid - 1];
    for (int i = beg; i < end; ++i) {
        off[i] = run;
        run += cnt[i];
    }
    if (tid == 1023) off[V] = E;
}

// ---- scatter edges into CSR buckets (atomic-free: off[t] + rank[e]) ----
__global__ void fill_kernel(const int* __restrict__ sidx, const int* __restrict__ tidx,
                            const float* __restrict__ esgn, const float* __restrict__ enorm,
                            const int* __restrict__ off, const int* __restrict__ rank,
                            int2* __restrict__ pk, int E) {
    int e = blockIdx.x * blockDim.x + threadIdx.x;
    if (e >= E) return;
    int idx = off[tidx[e]] + rank[e];
    float w = enorm[e] * esgn[e];
    pk[idx] = make_int2(sidx[e], __float_as_int(w));
}

// ---- one wave per target node: 16B bf16 gathers, 4 edges in flight/wave ----
// Output is written directly in MFMA A-fragment order (same layout as wTf).
__global__ __launch_bounds__(256) void accum_kernel(const unsigned short* __restrict__ vb,
                                                    const int2* __restrict__ pk,
                                                    const int* __restrict__ off,
                                                    unsigned short* __restrict__ ptrf, int V) {
    int gid = blockIdx.x * blockDim.x + threadIdx.x;
    int v = gid >> 6;
    if (v >= V) return;
    int lane = threadIdx.x & 63;
    int half = lane >> 5;     // edge parity handled by this half-wave
    int c = lane & 31;        // 16B chunk (8 bf16) within the row
    int beg = off[v], end = off[v + 1];
    const uint4* base = (const uint4*)vb;   // row = 32 uint4
    float acc[8];
#pragma unroll
    for (int j = 0; j < 8; ++j) acc[j] = 0.f;
    int i = beg + half;
    for (; i + 2 < end; i += 4) {            // 2 independent chains per half-wave
        int2 p0 = pk[i];
        int2 p1 = pk[i + 2];
        float w0 = __int_as_float(p0.y);
        float w1 = __int_as_float(p1.y);
        uint4 a = base[(size_t)p0.x * 32 + c];
        uint4 b = base[(size_t)p1.x * 32 + c];
        acc[0] = fmaf(__uint_as_float(a.x << 16), w0, acc[0]);
        acc[1] = fmaf(__uint_as_float(a.x & 0xffff0000u), w0, acc[1]);
        acc[2] = fmaf(__uint_as_float(a.y << 16), w0, acc[2]);
        acc[3] = fmaf(__uint_as_float(a.y & 0xffff0000u), w0, acc[3]);
        acc[4] = fmaf(__uint_as_float(a.z << 16), w0, acc[4]);
        acc[5] = fmaf(__uint_as_float(a.z & 0xffff0000u), w0, acc[5]);
        acc[6] = fmaf(__uint_as_float(a.w << 16), w0, acc[6]);
        acc[7] = fmaf(__uint_as_float(a.w & 0xffff0000u), w0, acc[7]);
        acc[0] = fmaf(__uint_as_float(b.x << 16), w1, acc[0]);
        acc[1] = fmaf(__uint_as_float(b.x & 0xffff0000u), w1, acc[1]);
        acc[2] = fmaf(__uint_as_float(b.y << 16), w1, acc[2]);
        acc[3] = fmaf(__uint_as_float(b.y & 0xffff0000u), w1, acc[3]);
        acc[4] = fmaf(__uint_as_float(b.z << 16), w1, acc[4]);
        acc[5] = fmaf(__uint_as_float(b.z & 0xffff0000u), w1, acc[5]);
        acc[6] = fmaf(__uint_as_float(b.w << 16), w1, acc[6]);
        acc[7] = fmaf(__uint_as_float(b.w & 0xffff0000u), w1, acc[7]);
    }
    if (i < end) {
        int2 p = pk[i];
        float w = __int_as_float(p.y);
        uint4 a = base[(size_t)p.x * 32 + c];
        acc[0] = fmaf(__uint_as_float(a.x << 16), w, acc[0]);
        acc[1] = fmaf(__uint_as_float(a.x & 0xffff0000u), w, acc[1]);
        acc[2] = fmaf(__uint_as_float(a.y << 16), w, acc[2]);
        acc[3] = fmaf(__uint_as_float(a.y & 0xffff0000u), w, acc[3]);
        acc[4] = fmaf(__uint_as_float(a.z << 16), w, acc[4]);
        acc[5] = fmaf(__uint_as_float(a.z & 0xffff0000u), w, acc[5]);
        acc[6] = fmaf(__uint_as_float(a.w << 16), w, acc[6]);
        acc[7] = fmaf(__uint_as_float(a.w & 0xffff0000u), w, acc[7]);
    }
#pragma unroll
    for (int j = 0; j < 8; ++j) acc[j] += __shfl_xor(acc[j], 32, 64);
    if (half == 0) {
        uint4 o;
        o.x = pack2(acc[0], acc[1]);
        o.y = pack2(acc[2], acc[3]);
        o.z = pack2(acc[4], acc[5]);
        o.w = pack2(acc[6], acc[7]);
        // A-fragment swizzled store: chunk c (k = 8c) of row v
        int fl = (v & 15) | ((c & 3) << 4);
        int unit = ((v >> 4) << 9) + ((c >> 2) << 6) + fl;
        ((uint4*)ptrf)[unit] = o;
    }
}

// ---- barrier-free dual-head GEMM + bias + softplus + rsample ----
// One wave per 16-row m-tile; A and B pre-swizzled into fragment order:
// zero LDS, zero __syncthreads, A read exactly once, B streamed from L2.
__global__ __launch_bounds__(256, 2) void head_mfma_kernel(const unsigned short* __restrict__ ptrf,
                                                           const unsigned short* __restrict__ wTf,
                                                           const float* __restrict__ lb,
                                                           const float* __restrict__ sb,
                                                           const float* __restrict__ eps,
                                                           float* __restrict__ out, int V) {
    int wave = threadIdx.x >> 6, lane = threadIdx.x & 63;
    int mt = blockIdx.x * 4 + wave;       // m-tile = 16 rows
    int v0 = mt << 4;
    if (v0 >= V) return;

    const s16x8* Af = (const s16x8*)ptrf + ((size_t)mt << 9) + lane;
    const s16x8* Bf = (const s16x8*)wTf + lane;

    s16x8 a[8];
#pragma unroll
    for (int kt = 0; kt < 8; ++kt) a[kt] = Af[kt << 6];

    f32x4 acc[32];
    f32x4 zero = {0.f, 0.f, 0.f, 0.f};
#pragma unroll
    for (int nt = 0; nt < 32; ++nt) acc[nt] = zero;

#pragma unroll
    for (int kt = 0; kt < 8; ++kt) {
#pragma unroll
        for (int nt = 0; nt < 32; ++nt) {
            s16x8 b = Bf[(nt << 9) + (kt << 6)];
            acc[nt] = __builtin_amdgcn_mfma_f32_16x16x32_bf16(a[kt], b, acc[nt], 0, 0, 0);
        }
    }

    int quad = lane >> 4, m16 = lane & 15;
    size_t VD = (size_t)V * D;
    bool full = (v0 + 16 <= V);
    const float* epsb = eps + (size_t)v0 * D;
    float* outb = out + (size_t)v0 * D;
#pragma unroll
    for (int nt = 0; nt < 16; ++nt) {
        int col = (nt << 4) + m16;
        float lbv = lb[col];
        float sbv = sb[col];
#pragma unroll
        for (int r = 0; r < 4; ++r) {
            int row = (quad << 2) + r;
            if (full || v0 + row < V) {
                int o = row * D + col;
                float lo = acc[nt][r] + lbv;
                float pre = acc[nt + 16][r] + sbv;
                float sp = fmaxf(pre, 0.f) + __logf(1.f + __expf(-fabsf(pre)));
                float st = sp + 1e-7f;
                float ep = __builtin_nontemporal_load(&epsb[o]);
                __builtin_nontemporal_store(lo, &outb[o]);
                __builtin_nontemporal_store(st, &outb[VD + o]);
                __builtin_nontemporal_store(fmaf(st, ep, lo), &outb[2 * VD + o]);
            }
        }
    }
}

extern "C" void kernel_launch(void* const* d_in, const int* in_sizes, int n_in,
                              void* d_out, int out_size, void* d_ws, size_t ws_size,
                              hipStream_t stream) {
    const float* vrepr = (const float*)d_in[0];
    const int*   sidx  = (const int*)d_in[1];
    const int*   tidx  = (const int*)d_in[2];
    const float* esgn  = (const float*)d_in[3];
    const float* enorm = (const float*)d_in[4];
    const float* loc_w = (const float*)d_in[5];
    const float* loc_b = (const float*)d_in[6];
    const float* std_w = (const float*)d_in[7];
    const float* std_b = (const float*)d_in[8];
    const float* eps   = (const float*)d_in[9];
    float* out = (float*)d_out;

    int E = in_sizes[1];
    int V = in_sizes[0] / D;

    char* ws = (char*)d_ws;
    size_t o = 0;
    unsigned short* vb   = (unsigned short*)(ws + o); o += (size_t)V * D * 2;
    unsigned short* ptrf = (unsigned short*)(ws + o); o += (size_t)V * D * 2;
    unsigned short* wTf  = (unsigned short*)(ws + o); o += (size_t)2 * D * D * 2;
    int* off  = (int*)(ws + o); o += ((size_t)V + 16) * sizeof(int);
    int* cnt  = (int*)(ws + o); o += ((size_t)V + 16) * sizeof(int);
    int* rank = (int*)(ws + o); o += (size_t)E * sizeof(int);
    o = (o + 15) & ~(size_t)15;
    int2* pk = (int2*)(ws + o); o += (size_t)E * sizeof(int2);

    hipMemsetAsync(cnt, 0, (size_t)V * sizeof(int), stream);
    prep_w_kernel<<<(2 * D * D) / 256, 256, 0, stream>>>(loc_w, std_w, wTf);
    conv_v_kernel<<<(V * (D / 8) + 255) / 256, 256, 0, stream>>>(vrepr, vb, V * (D / 8));
    hist_kernel<<<(E + 255) / 256, 256, 0, stream>>>(tidx, cnt, rank, E);
    scan_kernel<<<1, 1024, 0, stream>>>(cnt, off, V, E);
    fill_kernel<<<(E + 255) / 256, 256, 0, stream>>>(sidx, tidx, esgn, enorm, off, rank, pk, E);
    accum_kernel<<<(V * 64 + 255) / 256, 256, 0, stream>>>(vb, pk, off, ptrf, V);
    head_mfma_kernel<<<(V + 63) / 64, 256, 0, stream>>>(ptrf, wTf, loc_b, std_b, eps, out, V);
}

// Round 2
// 599.724 us; speedup vs baseline: 1.1633x; 1.1633x over previous
//
#include <hip/hip_runtime.h>

#define D 256

typedef __attribute__((ext_vector_type(8))) short s16x8;
typedef __attribute__((ext_vector_type(4))) float f32x4;

static __device__ __forceinline__ unsigned short f2b(float f) {
    unsigned u = __float_as_uint(f);
    unsigned r = (u + 0x7fffu + ((u >> 16) & 1u)) >> 16;   // RNE
    return (unsigned short)r;
}
static __device__ __forceinline__ unsigned pack2(float a, float b) {
    return (unsigned)f2b(a) | ((unsigned)f2b(b) << 16);
}

// async global->LDS, 16B per lane; LDS dest is wave-uniform base + lane*16
static __device__ __forceinline__ void gload_lds16(const void* g, void* l) {
    __builtin_amdgcn_global_load_lds((const __attribute__((address_space(1))) unsigned int*)g,
                                     (__attribute__((address_space(3))) unsigned int*)l,
                                     16, 0, 0);
}

// ---- cast both weight matrices to bf16, stored in MFMA B-fragment order ----
// Fragment layout (16x16x32 bf16): for tile t of 16 rows, k-tile kt (32 k),
// lane l = (row&15) | (((k>>3)&3)<<4) holds 8 contiguous bf16.
// unit index (16B units) = (t<<9) + (kt<<6) + lane.
__global__ void prep_w_kernel(const float* __restrict__ lw, const float* __restrict__ sw,
                              unsigned short* __restrict__ wTf) {
    int i = blockIdx.x * 256 + threadIdx.x;
    float v = (i < D * D) ? lw[i] : sw[i - D * D];
    int n = i >> 8;          // 0..511: concatenated [loc; std] output col
    int k = i & 255;
    int lane = (n & 15) | (((k >> 3) & 3) << 4);
    int unit = ((n >> 4) << 9) + ((k >> 5) << 6) + lane;
    wTf[unit * 8 + (k & 7)] = f2b(v);
}

// ---- cast vrepr to bf16, 32B read / 16B write per thread ----
__global__ void conv_v_kernel(const float* __restrict__ vr, unsigned short* __restrict__ vb, int n8) {
    int i = blockIdx.x * 256 + threadIdx.x;
    if (i < n8) {
        float4 f0 = ((const float4*)vr)[2 * i];
        float4 f1 = ((const float4*)vr)[2 * i + 1];
        uint4 o;
        o.x = pack2(f0.x, f0.y);
        o.y = pack2(f0.z, f0.w);
        o.z = pack2(f1.x, f1.y);
        o.w = pack2(f1.z, f1.w);
        ((uint4*)vb)[i] = o;
    }
}

// ---- histogram of target indices; records each edge's arrival rank ----
__global__ void hist_kernel(const int* __restrict__ tidx, int* __restrict__ cnt,
                            int* __restrict__ rank, int E) {
    int e = blockIdx.x * blockDim.x + threadIdx.x;
    if (e < E) rank[e] = atomicAdd(&cnt[tidx[e]], 1);
}

// ---- single-block exclusive scan over V counts ----
__global__ void scan_kernel(const int* __restrict__ cnt, int* __restrict__ off, int V, int E) {
    __shared__ int sums[1024];
    int tid = threadIdx.x;
    int CH = (V + 1023) >> 10;
    int beg = tid * CH;
    int end = min(beg + CH, V);
    int s = 0;
    for (int i = beg; i < end; ++i) s += cnt[i];
    sums[tid] = s;
    __syncthreads();
    for (int ofs = 1; ofs < 1024; ofs <<= 1) {
        int v = (tid >= ofs) ? sums[tid - ofs] : 0;
        __syncthreads();
        sums[tid] += v;
        __syncthreads();
    }
    int run = (tid == 0) ? 0 : sums[tid - 1];
    for (int i = beg; i < end; ++i) {
        off[i] = run;
        run += cnt[i];
    }
    if (tid == 1023) off[V] = E;
}

// ---- scatter edges into CSR buckets (atomic-free: off[t] + rank[e]) ----
__global__ void fill_kernel(const int* __restrict__ sidx, const int* __restrict__ tidx,
                            const float* __restrict__ esgn, const float* __restrict__ enorm,
                            const int* __restrict__ off, const int* __restrict__ rank,
                            int2* __restrict__ pk, int E) {
    int e = blockIdx.x * blockDim.x + threadIdx.x;
    if (e >= E) return;
    int idx = off[tidx[e]] + rank[e];
    float w = enorm[e] * esgn[e];
    pk[idx] = make_int2(sidx[e], __float_as_int(w));
}

// ---- one wave per target node: 16B bf16 gathers, 4 edges in flight/wave ----
// Output is written directly in MFMA A-fragment order (same layout as wTf).
__global__ __launch_bounds__(256) void accum_kernel(const unsigned short* __restrict__ vb,
                                                    const int2* __restrict__ pk,
                                                    const int* __restrict__ off,
                                                    unsigned short* __restrict__ ptrf, int V) {
    int gid = blockIdx.x * blockDim.x + threadIdx.x;
    int v = gid >> 6;
    if (v >= V) return;
    int lane = threadIdx.x & 63;
    int half = lane >> 5;     // edge parity handled by this half-wave
    int c = lane & 31;        // 16B chunk (8 bf16) within the row
    int beg = off[v], end = off[v + 1];
    const uint4* base = (const uint4*)vb;   // row = 32 uint4
    float acc[8];
#pragma unroll
    for (int j = 0; j < 8; ++j) acc[j] = 0.f;
    int i = beg + half;
    for (; i + 2 < end; i += 4) {            // 2 independent chains per half-wave
        int2 p0 = pk[i];
        int2 p1 = pk[i + 2];
        float w0 = __int_as_float(p0.y);
        float w1 = __int_as_float(p1.y);
        uint4 a = base[(size_t)p0.x * 32 + c];
        uint4 b = base[(size_t)p1.x * 32 + c];
        acc[0] = fmaf(__uint_as_float(a.x << 16), w0, acc[0]);
        acc[1] = fmaf(__uint_as_float(a.x & 0xffff0000u), w0, acc[1]);
        acc[2] = fmaf(__uint_as_float(a.y << 16), w0, acc[2]);
        acc[3] = fmaf(__uint_as_float(a.y & 0xffff0000u), w0, acc[3]);
        acc[4] = fmaf(__uint_as_float(a.z << 16), w0, acc[4]);
        acc[5] = fmaf(__uint_as_float(a.z & 0xffff0000u), w0, acc[5]);
        acc[6] = fmaf(__uint_as_float(a.w << 16), w0, acc[6]);
        acc[7] = fmaf(__uint_as_float(a.w & 0xffff0000u), w0, acc[7]);
        acc[0] = fmaf(__uint_as_float(b.x << 16), w1, acc[0]);
        acc[1] = fmaf(__uint_as_float(b.x & 0xffff0000u), w1, acc[1]);
        acc[2] = fmaf(__uint_as_float(b.y << 16), w1, acc[2]);
        acc[3] = fmaf(__uint_as_float(b.y & 0xffff0000u), w1, acc[3]);
        acc[4] = fmaf(__uint_as_float(b.z << 16), w1, acc[4]);
        acc[5] = fmaf(__uint_as_float(b.z & 0xffff0000u), w1, acc[5]);
        acc[6] = fmaf(__uint_as_float(b.w << 16), w1, acc[6]);
        acc[7] = fmaf(__uint_as_float(b.w & 0xffff0000u), w1, acc[7]);
    }
    if (i < end) {
        int2 p = pk[i];
        float w = __int_as_float(p.y);
        uint4 a = base[(size_t)p.x * 32 + c];
        acc[0] = fmaf(__uint_as_float(a.x << 16), w, acc[0]);
        acc[1] = fmaf(__uint_as_float(a.x & 0xffff0000u), w, acc[1]);
        acc[2] = fmaf(__uint_as_float(a.y << 16), w, acc[2]);
        acc[3] = fmaf(__uint_as_float(a.y & 0xffff0000u), w, acc[3]);
        acc[4] = fmaf(__uint_as_float(a.z << 16), w, acc[4]);
        acc[5] = fmaf(__uint_as_float(a.z & 0xffff0000u), w, acc[5]);
        acc[6] = fmaf(__uint_as_float(a.w << 16), w, acc[6]);
        acc[7] = fmaf(__uint_as_float(a.w & 0xffff0000u), w, acc[7]);
    }
#pragma unroll
    for (int j = 0; j < 8; ++j) acc[j] += __shfl_xor(acc[j], 32, 64);
    if (half == 0) {
        uint4 o;
        o.x = pack2(acc[0], acc[1]);
        o.y = pack2(acc[2], acc[3]);
        o.z = pack2(acc[4], acc[5]);
        o.w = pack2(acc[6], acc[7]);
        // A-fragment swizzled store: chunk c (k = 8c) of row v
        int fl = (v & 15) | ((c & 3) << 4);
        int unit = ((v >> 4) << 9) + ((c >> 2) << 6) + fl;
        ((uint4*)ptrf)[unit] = o;
    }
}

// ---- dual-head GEMM + bias + softplus + rsample ----
// Fragment-ordered A (registers, read once) and B (LDS double-buffered via
// global_load_lds). One barrier per k-tile; stage issued before compute so
// the vmcnt drain at the barrier lands after ~400cy of MFMA.
__global__ __launch_bounds__(256, 2) void head_mfma_kernel(const unsigned short* __restrict__ ptrf,
                                                           const unsigned short* __restrict__ wTf,
                                                           const float* __restrict__ lb,
                                                           const float* __restrict__ sb,
                                                           const float* __restrict__ eps,
                                                           float* __restrict__ out, int V) {
    __shared__ s16x8 Blds[2][2048];   // 2 x 32KB: one k-tile of all 32 n-tiles
    int tid = threadIdx.x;
    int wave = tid >> 6, lane = tid & 63;
    int mt = blockIdx.x * 4 + wave;       // m-tile = 16 rows
    int lastmt = (V - 1) >> 4;
    int mtc = mt > lastmt ? lastmt : mt;  // clamp: all waves stay for barriers
    int v0 = mt << 4;

    // A fragments: 8 x 16B per lane, read exactly once from HBM
    const s16x8* Af = (const s16x8*)ptrf + ((size_t)mtc << 9) + lane;
    s16x8 a[8];
#pragma unroll
    for (int kt = 0; kt < 8; ++kt) a[kt] = Af[kt << 6];

    const s16x8* Bf = (const s16x8*)wTf;

    f32x4 acc[32];
    f32x4 zero = {0.f, 0.f, 0.f, 0.f};
#pragma unroll
    for (int nt = 0; nt < 32; ++nt) acc[nt] = zero;

#define STAGE_B(KT, BUF)                                                      \
    {                                                                         \
        _Pragma("unroll")                                                     \
        for (int j = 0; j < 8; ++j) {                                         \
            int nt = j * 4 + wave;                                            \
            gload_lds16((const void*)(Bf + (nt << 9) + ((KT) << 6) + lane),   \
                        (void*)&Blds[BUF][nt << 6]);                          \
        }                                                                     \
    }

    STAGE_B(0, 0);
    __syncthreads();

#pragma unroll
    for (int kt = 0; kt < 8; ++kt) {
        int buf = kt & 1;
        if (kt < 7) STAGE_B(kt + 1, buf ^ 1);
#pragma unroll
        for (int nt = 0; nt < 32; ++nt) {
            s16x8 b = Blds[buf][(nt << 6) + lane];
            acc[nt] = __builtin_amdgcn_mfma_f32_16x16x32_bf16(a[kt], b, acc[nt], 0, 0, 0);
        }
        if (kt < 7) __syncthreads();
    }
#undef STAGE_B

    if (v0 < V) {   // V % 16 == 0: a live m-tile is always full
        int quad = lane >> 4, m16 = lane & 15;
        size_t VD = (size_t)V * D;
        const float* epsb = eps + (size_t)v0 * D;
        float* outb = out + (size_t)v0 * D;
#pragma unroll
        for (int nt = 0; nt < 16; ++nt) {
            int col = (nt << 4) + m16;
            float lbv = lb[col];
            float sbv = sb[col];
#pragma unroll
            for (int r = 0; r < 4; ++r) {
                int row = (quad << 2) + r;
                int o = row * D + col;
                float lo = acc[nt][r] + lbv;
                float pre = acc[nt + 16][r] + sbv;
                float sp = fmaxf(pre, 0.f) + __logf(1.f + __expf(-fabsf(pre)));
                float st = sp + 1e-7f;
                float ep = __builtin_nontemporal_load(&epsb[o]);
                outb[o] = lo;                       // normal stores: let L2
                outb[VD + o] = st;                  // merge 64B half-lines
                outb[2 * VD + o] = fmaf(st, ep, lo);
            }
        }
    }
}

extern "C" void kernel_launch(void* const* d_in, const int* in_sizes, int n_in,
                              void* d_out, int out_size, void* d_ws, size_t ws_size,
                              hipStream_t stream) {
    const float* vrepr = (const float*)d_in[0];
    const int*   sidx  = (const int*)d_in[1];
    const int*   tidx  = (const int*)d_in[2];
    const float* esgn  = (const float*)d_in[3];
    const float* enorm = (const float*)d_in[4];
    const float* loc_w = (const float*)d_in[5];
    const float* loc_b = (const float*)d_in[6];
    const float* std_w = (const float*)d_in[7];
    const float* std_b = (const float*)d_in[8];
    const float* eps   = (const float*)d_in[9];
    float* out = (float*)d_out;

    int E = in_sizes[1];
    int V = in_sizes[0] / D;

    char* ws = (char*)d_ws;
    size_t o = 0;
    unsigned short* vb   = (unsigned short*)(ws + o); o += (size_t)V * D * 2;
    unsigned short* ptrf = (unsigned short*)(ws + o); o += (size_t)V * D * 2;
    unsigned short* wTf  = (unsigned short*)(ws + o); o += (size_t)2 * D * D * 2;
    int* off  = (int*)(ws + o); o += ((size_t)V + 16) * sizeof(int);
    int* cnt  = (int*)(ws + o); o += ((size_t)V + 16) * sizeof(int);
    int* rank = (int*)(ws + o); o += (size_t)E * sizeof(int);
    o = (o + 15) & ~(size_t)15;
    int2* pk = (int2*)(ws + o); o += (size_t)E * sizeof(int2);

    hipMemsetAsync(cnt, 0, (size_t)V * sizeof(int), stream);
    prep_w_kernel<<<(2 * D * D) / 256, 256, 0, stream>>>(loc_w, std_w, wTf);
    conv_v_kernel<<<(V * (D / 8) + 255) / 256, 256, 0, stream>>>(vrepr, vb, V * (D / 8));
    hist_kernel<<<(E + 255) / 256, 256, 0, stream>>>(tidx, cnt, rank, E);
    scan_kernel<<<1, 1024, 0, stream>>>(cnt, off, V, E);
    fill_kernel<<<(E + 255) / 256, 256, 0, stream>>>(sidx, tidx, esgn, enorm, off, rank, pk, E);
    accum_kernel<<<(V * 64 + 255) / 256, 256, 0, stream>>>(vb, pk, off, ptrf, V);
    head_mfma_kernel<<<(V + 63) / 64, 256, 0, stream>>>(ptrf, wTf, loc_b, std_b, eps, out, V);
}

// Round 3
// 537.423 us; speedup vs baseline: 1.2982x; 1.1159x over previous
//
#include <hip/hip_runtime.h>

#define D 256

typedef __attribute__((ext_vector_type(8))) short s16x8;
typedef __attribute__((ext_vector_type(4))) float f32x4;

static __device__ __forceinline__ unsigned short f2b(float f) {
    unsigned u = __float_as_uint(f);
    unsigned r = (u + 0x7fffu + ((u >> 16) & 1u)) >> 16;   // RNE
    return (unsigned short)r;
}
static __device__ __forceinline__ unsigned pack2(float a, float b) {
    return (unsigned)f2b(a) | ((unsigned)f2b(b) << 16);
}

// async global->LDS, 16B per lane; LDS dest is wave-uniform base + lane*16
static __device__ __forceinline__ void gload_lds16(const void* g, void* l) {
    __builtin_amdgcn_global_load_lds((const __attribute__((address_space(1))) unsigned int*)g,
                                     (__attribute__((address_space(3))) unsigned int*)l,
                                     16, 0, 0);
}

// ---- cast both weight matrices to bf16, stored in MFMA B-fragment order ----
// Fragment layout (16x16x32 bf16): for tile t of 16 rows, k-tile kt (32 k),
// lane l = (row&15) | (((k>>3)&3)<<4) holds 8 contiguous bf16.
// unit index (16B units) = (t<<9) + (kt<<6) + lane.
__global__ void prep_w_kernel(const float* __restrict__ lw, const float* __restrict__ sw,
                              unsigned short* __restrict__ wTf) {
    int i = blockIdx.x * 256 + threadIdx.x;
    float v = (i < D * D) ? lw[i] : sw[i - D * D];
    int n = i >> 8;          // 0..511: concatenated [loc; std] output col
    int k = i & 255;
    int lane = (n & 15) | (((k >> 3) & 3) << 4);
    int unit = ((n >> 4) << 9) + ((k >> 5) << 6) + lane;
    wTf[unit * 8 + (k & 7)] = f2b(v);
}

// ---- cast vrepr to bf16, 32B read / 16B write per thread ----
__global__ void conv_v_kernel(const float* __restrict__ vr, unsigned short* __restrict__ vb, int n8) {
    int i = blockIdx.x * 256 + threadIdx.x;
    if (i < n8) {
        float4 f0 = ((const float4*)vr)[2 * i];
        float4 f1 = ((const float4*)vr)[2 * i + 1];
        uint4 o;
        o.x = pack2(f0.x, f0.y);
        o.y = pack2(f0.z, f0.w);
        o.z = pack2(f1.x, f1.y);
        o.w = pack2(f1.z, f1.w);
        ((uint4*)vb)[i] = o;
    }
}

// ---- histogram of target indices; records each edge's arrival rank ----
__global__ void hist_kernel(const int* __restrict__ tidx, int* __restrict__ cnt,
                            int* __restrict__ rank, int E) {
    int e = blockIdx.x * blockDim.x + threadIdx.x;
    if (e < E) rank[e] = atomicAdd(&cnt[tidx[e]], 1);
}

// ---- hierarchical scan: 49 blocks x 1024 elems -> 1 block -> 49 blocks ----
__global__ void scan1_kernel(const int* __restrict__ cnt, int* __restrict__ bsum, int V) {
    __shared__ int red[256];
    int b = blockIdx.x, tid = threadIdx.x;
    int base = b * 1024 + tid * 4;
    int s = 0;
    if (base + 3 < V) {
        int4 q = *(const int4*)&cnt[base];
        s = q.x + q.y + q.z + q.w;
    } else {
        for (int j = 0; j < 4; ++j)
            if (base + j < V) s += cnt[base + j];
    }
    red[tid] = s;
    __syncthreads();
    for (int ofs = 128; ofs > 0; ofs >>= 1) {
        if (tid < ofs) red[tid] += red[tid + ofs];
        __syncthreads();
    }
    if (tid == 0) bsum[b] = red[0];
}

__global__ void scan2_kernel(int* __restrict__ bsum, int nb) {
    __shared__ int s[256];
    int tid = threadIdx.x;
    int v = (tid < nb) ? bsum[tid] : 0;
    s[tid] = v;
    __syncthreads();
    for (int ofs = 1; ofs < 256; ofs <<= 1) {
        int t = (tid >= ofs) ? s[tid - ofs] : 0;
        __syncthreads();
        s[tid] += t;
        __syncthreads();
    }
    if (tid < nb) bsum[tid] = s[tid] - v;   // exclusive
}

__global__ void scan3_kernel(const int* __restrict__ cnt, const int* __restrict__ bsum,
                             int* __restrict__ off, int V, int E) {
    __shared__ int ts[256];
    int b = blockIdx.x, tid = threadIdx.x;
    int base = b * 1024 + tid * 4;
    int v0 = 0, v1 = 0, v2 = 0, v3 = 0;
    if (base + 3 < V) {
        int4 q = *(const int4*)&cnt[base];
        v0 = q.x; v1 = q.y; v2 = q.z; v3 = q.w;
    } else {
        if (base < V)     v0 = cnt[base];
        if (base + 1 < V) v1 = cnt[base + 1];
        if (base + 2 < V) v2 = cnt[base + 2];
        if (base + 3 < V) v3 = cnt[base + 3];
    }
    int tsum = v0 + v1 + v2 + v3;
    ts[tid] = tsum;
    __syncthreads();
    for (int ofs = 1; ofs < 256; ofs <<= 1) {
        int t = (tid >= ofs) ? ts[tid - ofs] : 0;
        __syncthreads();
        ts[tid] += t;
        __syncthreads();
    }
    int pre = bsum[b] + ts[tid] - tsum;
    if (base + 3 < V) {
        int4 o = make_int4(pre, pre + v0, pre + v0 + v1, pre + v0 + v1 + v2);
        *(int4*)&off[base] = o;
    } else {
        if (base < V)     off[base] = pre;
        if (base + 1 < V) off[base + 1] = pre + v0;
        if (base + 2 < V) off[base + 2] = pre + v0 + v1;
        if (base + 3 < V) off[base + 3] = pre + v0 + v1 + v2;
    }
    if (b == 0 && tid == 0) off[V] = E;
}

// ---- scatter edges into CSR buckets (atomic-free: off[t] + rank[e]) ----
__global__ void fill_kernel(const int* __restrict__ sidx, const int* __restrict__ tidx,
                            const float* __restrict__ esgn, const float* __restrict__ enorm,
                            const int* __restrict__ off, const int* __restrict__ rank,
                            int2* __restrict__ pk, int E) {
    int e = blockIdx.x * blockDim.x + threadIdx.x;
    if (e >= E) return;
    int idx = off[tidx[e]] + rank[e];
    float w = enorm[e] * esgn[e];
    pk[idx] = make_int2(sidx[e], __float_as_int(w));
}

#define FMA8(A, W)                                                   \
    acc[0] = fmaf(__uint_as_float((A).x << 16), (W), acc[0]);        \
    acc[1] = fmaf(__uint_as_float((A).x & 0xffff0000u), (W), acc[1]);\
    acc[2] = fmaf(__uint_as_float((A).y << 16), (W), acc[2]);        \
    acc[3] = fmaf(__uint_as_float((A).y & 0xffff0000u), (W), acc[3]);\
    acc[4] = fmaf(__uint_as_float((A).z << 16), (W), acc[4]);        \
    acc[5] = fmaf(__uint_as_float((A).z & 0xffff0000u), (W), acc[5]);\
    acc[6] = fmaf(__uint_as_float((A).w << 16), (W), acc[6]);        \
    acc[7] = fmaf(__uint_as_float((A).w & 0xffff0000u), (W), acc[7]);

// ---- one wave per target node: contiguous half-split, 4-deep gather chains ----
// (8 row-gathers in flight per wave). Output in MFMA A-fragment order.
__global__ __launch_bounds__(256) void accum_kernel(const unsigned short* __restrict__ vb,
                                                    const int2* __restrict__ pk,
                                                    const int* __restrict__ off,
                                                    unsigned short* __restrict__ ptrf, int V) {
    int gid = blockIdx.x * blockDim.x + threadIdx.x;
    int v = gid >> 6;
    if (v >= V) return;
    int lane = threadIdx.x & 63;
    int half = lane >> 5;     // each half-wave owns a contiguous range of edges
    int c = lane & 31;        // 16B chunk (8 bf16) within the row
    int beg = off[v], end = off[v + 1];
    int mid = beg + ((end - beg + 1) >> 1);
    int i = half ? mid : beg;
    int e = half ? end : mid;
    const uint4* base = (const uint4*)vb;   // row = 32 uint4
    float acc[8];
#pragma unroll
    for (int j = 0; j < 8; ++j) acc[j] = 0.f;
    for (; i + 3 < e; i += 4) {             // 4 independent gathers in flight
        int2 p0 = pk[i];
        int2 p1 = pk[i + 1];
        int2 p2 = pk[i + 2];
        int2 p3 = pk[i + 3];
        uint4 a0 = base[(size_t)p0.x * 32 + c];
        uint4 a1 = base[(size_t)p1.x * 32 + c];
        uint4 a2 = base[(size_t)p2.x * 32 + c];
        uint4 a3 = base[(size_t)p3.x * 32 + c];
        float w0 = __int_as_float(p0.y);
        float w1 = __int_as_float(p1.y);
        float w2 = __int_as_float(p2.y);
        float w3 = __int_as_float(p3.y);
        FMA8(a0, w0)
        FMA8(a1, w1)
        FMA8(a2, w2)
        FMA8(a3, w3)
    }
    for (; i < e; ++i) {
        int2 p = pk[i];
        float w = __int_as_float(p.y);
        uint4 a = base[(size_t)p.x * 32 + c];
        FMA8(a, w)
    }
#pragma unroll
    for (int j = 0; j < 8; ++j) acc[j] += __shfl_xor(acc[j], 32, 64);
    if (half == 0) {
        uint4 o;
        o.x = pack2(acc[0], acc[1]);
        o.y = pack2(acc[2], acc[3]);
        o.z = pack2(acc[4], acc[5]);
        o.w = pack2(acc[6], acc[7]);
        // A-fragment swizzled store: chunk c (k = 8c) of row v
        int fl = (v & 15) | ((c & 3) << 4);
        int unit = ((v >> 4) << 9) + ((c >> 2) << 6) + fl;
        ((uint4*)ptrf)[unit] = o;
    }
}

// ---- dual-head GEMM + bias + softplus + rsample ----
// Fragment-ordered A (registers, read once) and B (LDS double-buffered via
// global_load_lds). One barrier per k-tile; stage issued before compute so
// the vmcnt drain at the barrier lands after ~400cy of MFMA.
__global__ __launch_bounds__(256, 2) void head_mfma_kernel(const unsigned short* __restrict__ ptrf,
                                                           const unsigned short* __restrict__ wTf,
                                                           const float* __restrict__ lb,
                                                           const float* __restrict__ sb,
                                                           const float* __restrict__ eps,
                                                           float* __restrict__ out, int V) {
    __shared__ s16x8 Blds[2][2048];   // 2 x 32KB: one k-tile of all 32 n-tiles
    int tid = threadIdx.x;
    int wave = tid >> 6, lane = tid & 63;
    int mt = blockIdx.x * 4 + wave;       // m-tile = 16 rows
    int lastmt = (V - 1) >> 4;
    int mtc = mt > lastmt ? lastmt : mt;  // clamp: all waves stay for barriers
    int v0 = mt << 4;

    // A fragments: 8 x 16B per lane, read exactly once from HBM
    const s16x8* Af = (const s16x8*)ptrf + ((size_t)mtc << 9) + lane;
    s16x8 a[8];
#pragma unroll
    for (int kt = 0; kt < 8; ++kt) a[kt] = Af[kt << 6];

    const s16x8* Bf = (const s16x8*)wTf;

    f32x4 acc[32];
    f32x4 zero = {0.f, 0.f, 0.f, 0.f};
#pragma unroll
    for (int nt = 0; nt < 32; ++nt) acc[nt] = zero;

#define STAGE_B(KT, BUF)                                                      \
    {                                                                         \
        _Pragma("unroll")                                                     \
        for (int j = 0; j < 8; ++j) {                                         \
            int nt = j * 4 + wave;                                            \
            gload_lds16((const void*)(Bf + (nt << 9) + ((KT) << 6) + lane),   \
                        (void*)&Blds[BUF][nt << 6]);                          \
        }                                                                     \
    }

    STAGE_B(0, 0);
    __syncthreads();

#pragma unroll
    for (int kt = 0; kt < 8; ++kt) {
        int buf = kt & 1;
        if (kt < 7) STAGE_B(kt + 1, buf ^ 1);
#pragma unroll
        for (int nt = 0; nt < 32; ++nt) {
            s16x8 b = Blds[buf][(nt << 6) + lane];
            acc[nt] = __builtin_amdgcn_mfma_f32_16x16x32_bf16(a[kt], b, acc[nt], 0, 0, 0);
        }
        if (kt < 7) __syncthreads();
    }
#undef STAGE_B

    if (v0 < V) {   // V % 16 == 0: a live m-tile is always full
        int quad = lane >> 4, m16 = lane & 15;
        size_t VD = (size_t)V * D;
        const float* epsb = eps + (size_t)v0 * D;
        float* outb = out + (size_t)v0 * D;
#pragma unroll
        for (int nt = 0; nt < 16; ++nt) {
            int col = (nt << 4) + m16;
            float lbv = lb[col];
            float sbv = sb[col];
#pragma unroll
            for (int r = 0; r < 4; ++r) {
                int row = (quad << 2) + r;
                int o = row * D + col;
                float lo = acc[nt][r] + lbv;
                float pre = acc[nt + 16][r] + sbv;
                float sp = fmaxf(pre, 0.f) + __logf(1.f + __expf(-fabsf(pre)));
                float st = sp + 1e-7f;
                float ep = __builtin_nontemporal_load(&epsb[o]);
                outb[o] = lo;                       // normal stores: let L2
                outb[VD + o] = st;                  // merge 64B half-lines
                outb[2 * VD + o] = fmaf(st, ep, lo);
            }
        }
    }
}

extern "C" void kernel_launch(void* const* d_in, const int* in_sizes, int n_in,
                              void* d_out, int out_size, void* d_ws, size_t ws_size,
                              hipStream_t stream) {
    const float* vrepr = (const float*)d_in[0];
    const int*   sidx  = (const int*)d_in[1];
    const int*   tidx  = (const int*)d_in[2];
    const float* esgn  = (const float*)d_in[3];
    const float* enorm = (const float*)d_in[4];
    const float* loc_w = (const float*)d_in[5];
    const float* loc_b = (const float*)d_in[6];
    const float* std_w = (const float*)d_in[7];
    const float* std_b = (const float*)d_in[8];
    const float* eps   = (const float*)d_in[9];
    float* out = (float*)d_out;

    int E = in_sizes[1];
    int V = in_sizes[0] / D;

    char* ws = (char*)d_ws;
    size_t o = 0;
    unsigned short* vb   = (unsigned short*)(ws + o); o += (size_t)V * D * 2;
    unsigned short* ptrf = (unsigned short*)(ws + o); o += (size_t)V * D * 2;
    unsigned short* wTf  = (unsigned short*)(ws + o); o += (size_t)2 * D * D * 2;
    int* off  = (int*)(ws + o); o += ((size_t)V + 16) * sizeof(int);
    int* cnt  = (int*)(ws + o); o += ((size_t)V + 16) * sizeof(int);
    int* rank = (int*)(ws + o); o += (size_t)E * sizeof(int);
    int* bsum = (int*)(ws + o); o += 256 * sizeof(int);
    o = (o + 15) & ~(size_t)15;
    int2* pk = (int2*)(ws + o); o += (size_t)E * sizeof(int2);

    int nb = (V + 1023) >> 10;   // scan blocks (<=256)

    hipMemsetAsync(cnt, 0, (size_t)V * sizeof(int), stream);
    prep_w_kernel<<<(2 * D * D) / 256, 256, 0, stream>>>(loc_w, std_w, wTf);
    conv_v_kernel<<<(V * (D / 8) + 255) / 256, 256, 0, stream>>>(vrepr, vb, V * (D / 8));
    hist_kernel<<<(E + 255) / 256, 256, 0, stream>>>(tidx, cnt, rank, E);
    scan1_kernel<<<nb, 256, 0, stream>>>(cnt, bsum, V);
    scan2_kernel<<<1, 256, 0, stream>>>(bsum, nb);
    scan3_kernel<<<nb, 256, 0, stream>>>(cnt, bsum, off, V, E);
    fill_kernel<<<(E + 255) / 256, 256, 0, stream>>>(sidx, tidx, esgn, enorm, off, rank, pk, E);
    accum_kernel<<<(V * 64 + 255) / 256, 256, 0, stream>>>(vb, pk, off, ptrf, V);
    head_mfma_kernel<<<(V + 63) / 64, 256, 0, stream>>>(ptrf, wTf, loc_b, std_b, eps, out, V);
}

// Round 4
// 525.153 us; speedup vs baseline: 1.3285x; 1.0234x over previous
//
#include <hip/hip_runtime.h>

#define D 256

typedef __attribute__((ext_vector_type(8))) short s16x8;
typedef __attribute__((ext_vector_type(4))) float f32x4;

static __device__ __forceinline__ unsigned short f2b(float f) {
    unsigned u = __float_as_uint(f);
    unsigned r = (u + 0x7fffu + ((u >> 16) & 1u)) >> 16;   // RNE
    return (unsigned short)r;
}
static __device__ __forceinline__ unsigned pack2(float a, float b) {
    return (unsigned)f2b(a) | ((unsigned)f2b(b) << 16);
}

// async global->LDS, 16B per lane; LDS dest is wave-uniform base + lane*16
static __device__ __forceinline__ void gload_lds16(const void* g, void* l) {
    __builtin_amdgcn_global_load_lds((const __attribute__((address_space(1))) unsigned int*)g,
                                     (__attribute__((address_space(3))) unsigned int*)l,
                                     16, 0, 0);
}

// ---- cast both weight matrices to bf16, stored in MFMA B-fragment order ----
// Fragment layout (16x16x32 bf16): for tile t of 16 rows, k-tile kt (32 k),
// lane l = (row&15) | (((k>>3)&3)<<4) holds 8 contiguous bf16.
// unit index (16B units) = (t<<9) + (kt<<6) + lane.
__global__ void prep_w_kernel(const float* __restrict__ lw, const float* __restrict__ sw,
                              unsigned short* __restrict__ wTf) {
    int i = blockIdx.x * 256 + threadIdx.x;
    float v = (i < D * D) ? lw[i] : sw[i - D * D];
    int n = i >> 8;          // 0..511: concatenated [loc; std] output col
    int k = i & 255;
    int lane = (n & 15) | (((k >> 3) & 3) << 4);
    int unit = ((n >> 4) << 9) + ((k >> 5) << 6) + lane;
    wTf[unit * 8 + (k & 7)] = f2b(v);
}

// ---- cast vrepr to bf16, 32B read / 16B write per thread ----
__global__ void conv_v_kernel(const float* __restrict__ vr, unsigned short* __restrict__ vb, int n8) {
    int i = blockIdx.x * 256 + threadIdx.x;
    if (i < n8) {
        float4 f0 = ((const float4*)vr)[2 * i];
        float4 f1 = ((const float4*)vr)[2 * i + 1];
        uint4 o;
        o.x = pack2(f0.x, f0.y);
        o.y = pack2(f0.z, f0.w);
        o.z = pack2(f1.x, f1.y);
        o.w = pack2(f1.z, f1.w);
        ((uint4*)vb)[i] = o;
    }
}

// ---- histogram of target indices; records each edge's arrival rank ----
__global__ void hist_kernel(const int* __restrict__ tidx, int* __restrict__ cnt,
                            int* __restrict__ rank, int E) {
    int e = blockIdx.x * blockDim.x + threadIdx.x;
    if (e < E) rank[e] = atomicAdd(&cnt[tidx[e]], 1);
}

// ---- hierarchical scan: 49 blocks x 1024 elems -> 1 block -> 49 blocks ----
__global__ void scan1_kernel(const int* __restrict__ cnt, int* __restrict__ bsum, int V) {
    __shared__ int red[256];
    int b = blockIdx.x, tid = threadIdx.x;
    int base = b * 1024 + tid * 4;
    int s = 0;
    if (base + 3 < V) {
        int4 q = *(const int4*)&cnt[base];
        s = q.x + q.y + q.z + q.w;
    } else {
        for (int j = 0; j < 4; ++j)
            if (base + j < V) s += cnt[base + j];
    }
    red[tid] = s;
    __syncthreads();
    for (int ofs = 128; ofs > 0; ofs >>= 1) {
        if (tid < ofs) red[tid] += red[tid + ofs];
        __syncthreads();
    }
    if (tid == 0) bsum[b] = red[0];
}

__global__ void scan2_kernel(int* __restrict__ bsum, int nb) {
    __shared__ int s[256];
    int tid = threadIdx.x;
    int v = (tid < nb) ? bsum[tid] : 0;
    s[tid] = v;
    __syncthreads();
    for (int ofs = 1; ofs < 256; ofs <<= 1) {
        int t = (tid >= ofs) ? s[tid - ofs] : 0;
        __syncthreads();
        s[tid] += t;
        __syncthreads();
    }
    if (tid < nb) bsum[tid] = s[tid] - v;   // exclusive
}

__global__ void scan3_kernel(const int* __restrict__ cnt, const int* __restrict__ bsum,
                             int* __restrict__ off, int V, int E) {
    __shared__ int ts[256];
    int b = blockIdx.x, tid = threadIdx.x;
    int base = b * 1024 + tid * 4;
    int v0 = 0, v1 = 0, v2 = 0, v3 = 0;
    if (base + 3 < V) {
        int4 q = *(const int4*)&cnt[base];
        v0 = q.x; v1 = q.y; v2 = q.z; v3 = q.w;
    } else {
        if (base < V)     v0 = cnt[base];
        if (base + 1 < V) v1 = cnt[base + 1];
        if (base + 2 < V) v2 = cnt[base + 2];
        if (base + 3 < V) v3 = cnt[base + 3];
    }
    int tsum = v0 + v1 + v2 + v3;
    ts[tid] = tsum;
    __syncthreads();
    for (int ofs = 1; ofs < 256; ofs <<= 1) {
        int t = (tid >= ofs) ? ts[tid - ofs] : 0;
        __syncthreads();
        ts[tid] += t;
        __syncthreads();
    }
    int pre = bsum[b] + ts[tid] - tsum;
    if (base + 3 < V) {
        int4 o = make_int4(pre, pre + v0, pre + v0 + v1, pre + v0 + v1 + v2);
        *(int4*)&off[base] = o;
    } else {
        if (base < V)     off[base] = pre;
        if (base + 1 < V) off[base + 1] = pre + v0;
        if (base + 2 < V) off[base + 2] = pre + v0 + v1;
        if (base + 3 < V) off[base + 3] = pre + v0 + v1 + v2;
    }
    if (b == 0 && tid == 0) off[V] = E;
}

// ---- scatter edges into CSR buckets (atomic-free: off[t] + rank[e]) ----
__global__ void fill_kernel(const int* __restrict__ sidx, const int* __restrict__ tidx,
                            const float* __restrict__ esgn, const float* __restrict__ enorm,
                            const int* __restrict__ off, const int* __restrict__ rank,
                            int2* __restrict__ pk, int E) {
    int e = blockIdx.x * blockDim.x + threadIdx.x;
    if (e >= E) return;
    int idx = off[tidx[e]] + rank[e];
    float w = enorm[e] * esgn[e];
    pk[idx] = make_int2(sidx[e], __float_as_int(w));
}

#define FMA8(A, W)                                                   \
    acc[0] = fmaf(__uint_as_float((A).x << 16), (W), acc[0]);        \
    acc[1] = fmaf(__uint_as_float((A).x & 0xffff0000u), (W), acc[1]);\
    acc[2] = fmaf(__uint_as_float((A).y << 16), (W), acc[2]);        \
    acc[3] = fmaf(__uint_as_float((A).y & 0xffff0000u), (W), acc[3]);\
    acc[4] = fmaf(__uint_as_float((A).z << 16), (W), acc[4]);        \
    acc[5] = fmaf(__uint_as_float((A).z & 0xffff0000u), (W), acc[5]);\
    acc[6] = fmaf(__uint_as_float((A).w << 16), (W), acc[6]);        \
    acc[7] = fmaf(__uint_as_float((A).w & 0xffff0000u), (W), acc[7]);

// ---- one wave per target node: contiguous half-split, 4-deep gather chains ----
// (8 row-gathers in flight per wave). Output in MFMA A-fragment order.
__global__ __launch_bounds__(256) void accum_kernel(const unsigned short* __restrict__ vb,
                                                    const int2* __restrict__ pk,
                                                    const int* __restrict__ off,
                                                    unsigned short* __restrict__ ptrf, int V) {
    int gid = blockIdx.x * blockDim.x + threadIdx.x;
    int v = gid >> 6;
    if (v >= V) return;
    int lane = threadIdx.x & 63;
    int half = lane >> 5;     // each half-wave owns a contiguous range of edges
    int c = lane & 31;        // 16B chunk (8 bf16) within the row
    int beg = off[v], end = off[v + 1];
    int mid = beg + ((end - beg + 1) >> 1);
    int i = half ? mid : beg;
    int e = half ? end : mid;
    const uint4* base = (const uint4*)vb;   // row = 32 uint4
    float acc[8];
#pragma unroll
    for (int j = 0; j < 8; ++j) acc[j] = 0.f;
    for (; i + 3 < e; i += 4) {             // 4 independent gathers in flight
        int2 p0 = pk[i];
        int2 p1 = pk[i + 1];
        int2 p2 = pk[i + 2];
        int2 p3 = pk[i + 3];
        uint4 a0 = base[(size_t)p0.x * 32 + c];
        uint4 a1 = base[(size_t)p1.x * 32 + c];
        uint4 a2 = base[(size_t)p2.x * 32 + c];
        uint4 a3 = base[(size_t)p3.x * 32 + c];
        float w0 = __int_as_float(p0.y);
        float w1 = __int_as_float(p1.y);
        float w2 = __int_as_float(p2.y);
        float w3 = __int_as_float(p3.y);
        FMA8(a0, w0)
        FMA8(a1, w1)
        FMA8(a2, w2)
        FMA8(a3, w3)
    }
    for (; i < e; ++i) {
        int2 p = pk[i];
        float w = __int_as_float(p.y);
        uint4 a = base[(size_t)p.x * 32 + c];
        FMA8(a, w)
    }
#pragma unroll
    for (int j = 0; j < 8; ++j) acc[j] += __shfl_xor(acc[j], 32, 64);
    if (half == 0) {
        uint4 o;
        o.x = pack2(acc[0], acc[1]);
        o.y = pack2(acc[2], acc[3]);
        o.z = pack2(acc[4], acc[5]);
        o.w = pack2(acc[6], acc[7]);
        // A-fragment swizzled store: chunk c (k = 8c) of row v
        int fl = (v & 15) | ((c & 3) << 4);
        int unit = ((v >> 4) << 9) + ((c >> 2) << 6) + fl;
        ((uint4*)ptrf)[unit] = o;
    }
}

// ---- dual-head GEMM + bias + softplus + rsample, n-split across 2 blocks ----
// Block nhalf owns loc-cols [128*nhalf,128*nhalf+128) AND matching std-cols,
// so the vsample fusion stays local. LDS 2x16KB -> ~4-5 blocks/CU resident;
// barrier drains hide under other blocks' compute. A read twice (once/n-half).
__global__ __launch_bounds__(256, 4) void head_mfma_kernel(const unsigned short* __restrict__ ptrf,
                                                           const unsigned short* __restrict__ wTf,
                                                           const float* __restrict__ lb,
                                                           const float* __restrict__ sb,
                                                           const float* __restrict__ eps,
                                                           float* __restrict__ out, int V) {
    __shared__ s16x8 Blds[2][1024];   // 2 x 16KB: one k-tile of this block's 16 n-tiles
    int tid = threadIdx.x;
    int wave = tid >> 6, lane = tid & 63;
    int nhalf = blockIdx.x;               // 0/1: which 128-col slice of each head
    int nb = nhalf << 3;                  // base n-tile within a head
    int mt = blockIdx.y * 4 + wave;       // m-tile = 16 rows
    int lastmt = (V - 1) >> 4;
    int mtc = mt > lastmt ? lastmt : mt;  // clamp: all waves stay for barriers
    int v0 = mt << 4;

    // A fragments: 8 x 16B per lane
    const s16x8* Af = (const s16x8*)ptrf + ((size_t)mtc << 9) + lane;
    s16x8 a[8];
#pragma unroll
    for (int kt = 0; kt < 8; ++kt) a[kt] = Af[kt << 6];

    const s16x8* Bf = (const s16x8*)wTf;

    f32x4 acc[16];
    f32x4 zero = {0.f, 0.f, 0.f, 0.f};
#pragma unroll
    for (int nt = 0; nt < 16; ++nt) acc[nt] = zero;

    // local n index ln 0..15 -> global n-tile: loc block then std block
#define STAGE_B(KT, BUF)                                                      \
    {                                                                         \
        _Pragma("unroll")                                                     \
        for (int j = 0; j < 4; ++j) {                                         \
            int ln = j * 4 + wave;                                            \
            int nt = (ln < 8) ? (nb + ln) : (16 + nb + (ln - 8));             \
            gload_lds16((const void*)(Bf + (nt << 9) + ((KT) << 6) + lane),   \
                        (void*)&Blds[BUF][ln << 6]);                          \
        }                                                                     \
    }

    STAGE_B(0, 0);
    __syncthreads();

#pragma unroll
    for (int kt = 0; kt < 8; ++kt) {
        int buf = kt & 1;
        if (kt < 7) STAGE_B(kt + 1, buf ^ 1);
#pragma unroll
        for (int ln = 0; ln < 16; ++ln) {
            s16x8 b = Blds[buf][(ln << 6) + lane];
            acc[ln] = __builtin_amdgcn_mfma_f32_16x16x32_bf16(a[kt], b, acc[ln], 0, 0, 0);
        }
        if (kt < 7) __syncthreads();
    }
#undef STAGE_B

    if (v0 < V) {   // V % 16 == 0: a live m-tile is always full
        int quad = lane >> 4, m16 = lane & 15;
        size_t VD = (size_t)V * D;
        const float* epsb = eps + (size_t)v0 * D;
        float* outb = out + (size_t)v0 * D;
#pragma unroll
        for (int ln = 0; ln < 8; ++ln) {
            int col = (nhalf << 7) + (ln << 4) + m16;
            float lbv = lb[col];
            float sbv = sb[col];
#pragma unroll
            for (int r = 0; r < 4; ++r) {
                int row = (quad << 2) + r;
                int o = row * D + col;
                float lo = acc[ln][r] + lbv;
                float pre = acc[ln + 8][r] + sbv;
                float sp = fmaxf(pre, 0.f) + __logf(1.f + __expf(-fabsf(pre)));
                float st = sp + 1e-7f;
                float ep = __builtin_nontemporal_load(&epsb[o]);
                outb[o] = lo;                       // normal stores: let L2
                outb[VD + o] = st;                  // merge 64B half-lines
                outb[2 * VD + o] = fmaf(st, ep, lo);
            }
        }
    }
}

extern "C" void kernel_launch(void* const* d_in, const int* in_sizes, int n_in,
                              void* d_out, int out_size, void* d_ws, size_t ws_size,
                              hipStream_t stream) {
    const float* vrepr = (const float*)d_in[0];
    const int*   sidx  = (const int*)d_in[1];
    const int*   tidx  = (const int*)d_in[2];
    const float* esgn  = (const float*)d_in[3];
    const float* enorm = (const float*)d_in[4];
    const float* loc_w = (const float*)d_in[5];
    const float* loc_b = (const float*)d_in[6];
    const float* std_w = (const float*)d_in[7];
    const float* std_b = (const float*)d_in[8];
    const float* eps   = (const float*)d_in[9];
    float* out = (float*)d_out;

    int E = in_sizes[1];
    int V = in_sizes[0] / D;

    char* ws = (char*)d_ws;
    size_t o = 0;
    unsigned short* vb   = (unsigned short*)(ws + o); o += (size_t)V * D * 2;
    unsigned short* ptrf = (unsigned short*)(ws + o); o += (size_t)V * D * 2;
    unsigned short* wTf  = (unsigned short*)(ws + o); o += (size_t)2 * D * D * 2;
    int* off  = (int*)(ws + o); o += ((size_t)V + 16) * sizeof(int);
    int* cnt  = (int*)(ws + o); o += ((size_t)V + 16) * sizeof(int);
    int* rank = (int*)(ws + o); o += (size_t)E * sizeof(int);
    int* bsum = (int*)(ws + o); o += 256 * sizeof(int);
    o = (o + 15) & ~(size_t)15;
    int2* pk = (int2*)(ws + o); o += (size_t)E * sizeof(int2);

    int nb = (V + 1023) >> 10;   // scan blocks (<=256)

    hipMemsetAsync(cnt, 0, (size_t)V * sizeof(int), stream);
    prep_w_kernel<<<(2 * D * D) / 256, 256, 0, stream>>>(loc_w, std_w, wTf);
    conv_v_kernel<<<(V * (D / 8) + 255) / 256, 256, 0, stream>>>(vrepr, vb, V * (D / 8));
    hist_kernel<<<(E + 255) / 256, 256, 0, stream>>>(tidx, cnt, rank, E);
    scan1_kernel<<<nb, 256, 0, stream>>>(cnt, bsum, V);
    scan2_kernel<<<1, 256, 0, stream>>>(bsum, nb);
    scan3_kernel<<<nb, 256, 0, stream>>>(cnt, bsum, off, V, E);
    fill_kernel<<<(E + 255) / 256, 256, 0, stream>>>(sidx, tidx, esgn, enorm, off, rank, pk, E);
    accum_kernel<<<(V * 64 + 255) / 256, 256, 0, stream>>>(vb, pk, off, ptrf, V);
    dim3 hgrid(2, (V + 63) / 64);
    head_mfma_kernel<<<hgrid, 256, 0, stream>>>(ptrf, wTf, loc_b, std_b, eps, out, V);
}